// Round 1
// baseline (282.931 us; speedup 1.0000x reference)
//
#include <hip/hip_runtime.h>
#include <hip/hip_bf16.h>
#include <math.h>

// Problem constants (fixed by setup_inputs)
#define B_     2
#define N_     2048
#define DA     128
#define H_     4
#define DH     32
#define DFF    512
#define DM     512
#define NT     512
#define NP     16384
#define MAXL   64          // max atoms per token group (Poisson(4): P(>64) ~ 0)

// ---------------- LayerNorm (one block = one row, 64 threads) ----------------
__global__ __launch_bounds__(64) void ln_kernel(const float* __restrict__ x,
                                                const float* __restrict__ g,
                                                const float* __restrict__ b,
                                                float* __restrict__ y) {
    int row = blockIdx.x;
    int t = threadIdx.x;
    const float* xr = x + row * DA;
    float a0 = xr[t], a1 = xr[t + 64];
    float s = a0 + a1, sq = a0 * a0 + a1 * a1;
#pragma unroll
    for (int m = 32; m; m >>= 1) {
        s += __shfl_xor(s, m);
        sq += __shfl_xor(sq, m);
    }
    float mean = s * (1.f / 128.f);
    float var = sq * (1.f / 128.f) - mean * mean;
    float inv = rsqrtf(var + 1e-5f);
    y[row * DA + t]      = (a0 - mean) * inv * g[t] + b[t];
    y[row * DA + t + 64] = (a1 - mean) * inv * g[t + 64] + b[t + 64];
}

// ------------- QKVG projection: (4096x128) @ (128x512) -> qkvg ---------------
// out layout per row: [0:128)=Q, [128:256)=K, [256:384)=V, [384:512)=G
__global__ __launch_bounds__(256) void qkvg_kernel(const float* __restrict__ qn,
                                                   const float* __restrict__ wq,
                                                   const float* __restrict__ wk,
                                                   const float* __restrict__ wv,
                                                   const float* __restrict__ wg,
                                                   float* __restrict__ out) {
    __shared__ float as[16][DA];
    int base = blockIdx.x * 16;
    int tid = threadIdx.x;
    for (int idx = tid; idx < 16 * DA; idx += 256)
        as[idx >> 7][idx & 127] = qn[base * DA + idx];
    __syncthreads();
    // c0 = tid in [0,256) -> Q or K; c1 = tid+256 -> V or G
    const float* wp0 = (tid < 128) ? (wq + tid) : (wk + tid - 128);
    const float* wp1 = (tid < 128) ? (wv + tid) : (wg + tid - 128);
    float acc0[16], acc1[16];
#pragma unroll
    for (int r = 0; r < 16; r++) { acc0[r] = 0.f; acc1[r] = 0.f; }
    for (int k = 0; k < DA; k += 4) {
        float w0[4], w1[4];
#pragma unroll
        for (int u = 0; u < 4; u++) {
            w0[u] = wp0[(k + u) * DA];
            w1[u] = wp1[(k + u) * DA];
        }
#pragma unroll
        for (int r = 0; r < 16; r++) {
            float4 a = *(const float4*)&as[r][k];
            acc0[r] += a.x * w0[0] + a.y * w0[1] + a.z * w0[2] + a.w * w0[3];
            acc1[r] += a.x * w1[0] + a.y * w1[1] + a.z * w1[2] + a.w * w1[3];
        }
    }
    int c0 = tid, c1 = tid + 256;
    for (int r = 0; r < 16; r++) {
        out[(base + r) * 512 + c0] = acc0[r];
        out[(base + r) * 512 + c1] = acc1[r];
    }
}

// ---------------- token counts + starts ----------------
__global__ void count_kernel(const int* __restrict__ tok, int* __restrict__ cnt) {
    int i = blockIdx.x * blockDim.x + threadIdx.x;
    if (i < B_ * N_) {
        int b = i >> 11;
        atomicAdd(&cnt[b * NT + tok[i]], 1);
    }
}

__global__ void scan_kernel(const int* __restrict__ cnt, int* __restrict__ tst) {
    if (threadIdx.x == 0) {
        int b = blockIdx.x;
        int acc = 0;
        for (int t = 0; t < NT; t++) {
            tst[b * NT + t] = acc;
            acc += cnt[b * NT + t];
        }
    }
}

// ---------------- pair bias: winner pass (last-write-wins = max pair idx) ----
__global__ void pair_win_kernel(const int* __restrict__ pidx,
                                const int* __restrict__ tok,
                                const int* __restrict__ tst,
                                int* __restrict__ winner) {
    int p = blockIdx.x * 256 + threadIdx.x;   // 0..32767
    if (p >= B_ * NP) return;
    int b = p >> 14, pp = p & (NP - 1);
    int src = pidx[p * 2], dst = pidx[p * 2 + 1];
    int ts = tok[b * N_ + src], td = tok[b * N_ + dst];
    if (ts == td) {
        int jj = dst - tst[b * NT + td];
        if (jj < MAXL) atomicMax(&winner[(b * N_ + src) * MAXL + jj], pp);
    }
}

__global__ void pair_bias_kernel(const int* __restrict__ pidx,
                                 const int* __restrict__ tok,
                                 const int* __restrict__ tst,
                                 const int* __restrict__ winner,
                                 const float* __restrict__ plm,
                                 const float* __restrict__ pbw,
                                 const float* __restrict__ pbb,
                                 float* __restrict__ biasc) {
    int p = blockIdx.x * 256 + threadIdx.x;
    if (p >= B_ * NP) return;
    int b = p >> 14, pp = p & (NP - 1);
    int src = pidx[p * 2], dst = pidx[p * 2 + 1];
    int ts = tok[b * N_ + src], td = tok[b * N_ + dst];
    if (ts == td) {
        int jj = dst - tst[b * NT + td];
        if (jj < MAXL && winner[(b * N_ + src) * MAXL + jj] == pp) {
            const float* pl = plm + p * 16;
#pragma unroll
            for (int h = 0; h < H_; h++) {
                float s = pbb[h];
#pragma unroll
                for (int f = 0; f < 16; f++) s += pl[f] * pbw[f * H_ + h];
                biasc[((b * N_ + src) * MAXL + jj) * H_ + h] = s;
            }
        }
    }
}

// ---------------- grouped attention (one block per atom, 128 thr = 4h x 32d) -
__global__ __launch_bounds__(128) void attn_kernel(const float* __restrict__ qkvg,
                                                   const int* __restrict__ tok,
                                                   const int* __restrict__ tst,
                                                   const int* __restrict__ cnt,
                                                   const int* __restrict__ winner,
                                                   const float* __restrict__ biasc,
                                                   float* __restrict__ att) {
    __shared__ float sc[H_][MAXL];
    int blk = blockIdx.x;                 // b*2048 + i
    int b = blk >> 11;
    int h = threadIdx.x >> 5, d = threadIdx.x & 31;
    int t = tok[blk];
    int start = tst[b * NT + t];
    int L = cnt[b * NT + t];
    if (L > MAXL) L = MAXL;
    float qv = qkvg[blk * 512 + h * DH + d];
    const float scale = 0.17677669529663687f;   // 1/sqrt(32)
    for (int jj = 0; jj < L; jj++) {
        int j = b * N_ + start + jj;
        float kv = qkvg[j * 512 + 128 + h * DH + d];
        float s = qv * kv;
#pragma unroll
        for (int m = 16; m; m >>= 1) s += __shfl_xor(s, m, 32);
        s *= scale;
        if (winner[blk * MAXL + jj] >= 0) s += biasc[(blk * MAXL + jj) * H_ + h];
        if (d == 0) sc[h][jj] = s;
    }
    __syncthreads();
    float mx = -1e30f;
    for (int jj = 0; jj < L; jj++) mx = fmaxf(mx, sc[h][jj]);
    float denom = 0.f, acc = 0.f;
    for (int jj = 0; jj < L; jj++) {
        float pj = expf(sc[h][jj] - mx);
        denom += pj;
        acc += pj * qkvg[(b * N_ + start + jj) * 512 + 256 + h * DH + d];
    }
    att[blk * DA + h * DH + d] = acc / denom;
}

// -------- out-proj + gate: qbuf = c_atom + sigmoid(G) * (att @ w_o) ----------
__global__ __launch_bounds__(128) void outproj_kernel(const float* __restrict__ att,
                                                      const float* __restrict__ wo,
                                                      const float* __restrict__ qkvg,
                                                      const float* __restrict__ c_atom,
                                                      float* __restrict__ qbuf) {
    __shared__ float as[16][DA];
    int base = blockIdx.x * 16;
    int tid = threadIdx.x;     // column 0..127
    for (int idx = tid; idx < 16 * DA; idx += 128)
        as[idx >> 7][idx & 127] = att[base * DA + idx];
    __syncthreads();
    float acc[16];
#pragma unroll
    for (int r = 0; r < 16; r++) acc[r] = 0.f;
    for (int k = 0; k < DA; k += 4) {
        float w[4];
#pragma unroll
        for (int u = 0; u < 4; u++) w[u] = wo[(k + u) * DA + tid];
#pragma unroll
        for (int r = 0; r < 16; r++) {
            float4 a = *(const float4*)&as[r][k];
            acc[r] += a.x * w[0] + a.y * w[1] + a.z * w[2] + a.w * w[3];
        }
    }
    for (int r = 0; r < 16; r++) {
        int row = base + r;
        float g = qkvg[row * 512 + 384 + tid];
        float sg = 1.f / (1.f + expf(-g));
        qbuf[row * DA + tid] = c_atom[row * DA + tid] + sg * acc[r];
    }
}

// -------- FFN part 1: u = silu(h@w1) * (h@w2), (4096x128)@(128x512) ----------
__global__ __launch_bounds__(256) void ffn1_kernel(const float* __restrict__ h,
                                                   const float* __restrict__ w1,
                                                   const float* __restrict__ w2,
                                                   float* __restrict__ u) {
    __shared__ float hs[16][DA];
    int base = blockIdx.x * 16;
    int tid = threadIdx.x;
    for (int idx = tid; idx < 16 * DA; idx += 256)
        hs[idx >> 7][idx & 127] = h[base * DA + idx];
    __syncthreads();
    int c0 = tid, c1 = tid + 256;
    float a10[16], a11[16], a20[16], a21[16];
#pragma unroll
    for (int r = 0; r < 16; r++) { a10[r] = 0.f; a11[r] = 0.f; a20[r] = 0.f; a21[r] = 0.f; }
    for (int k = 0; k < DA; k += 4) {
        float w10[4], w11[4], w20[4], w21[4];
#pragma unroll
        for (int uu = 0; uu < 4; uu++) {
            w10[uu] = w1[(k + uu) * DFF + c0];
            w11[uu] = w1[(k + uu) * DFF + c1];
            w20[uu] = w2[(k + uu) * DFF + c0];
            w21[uu] = w2[(k + uu) * DFF + c1];
        }
#pragma unroll
        for (int r = 0; r < 16; r++) {
            float4 a = *(const float4*)&hs[r][k];
            a10[r] += a.x * w10[0] + a.y * w10[1] + a.z * w10[2] + a.w * w10[3];
            a11[r] += a.x * w11[0] + a.y * w11[1] + a.z * w11[2] + a.w * w11[3];
            a20[r] += a.x * w20[0] + a.y * w20[1] + a.z * w20[2] + a.w * w20[3];
            a21[r] += a.x * w21[0] + a.y * w21[1] + a.z * w21[2] + a.w * w21[3];
        }
    }
    for (int r = 0; r < 16; r++) {
        float x0 = a10[r], x1 = a11[r];
        float s0 = x0 / (1.f + expf(-x0));
        float s1 = x1 / (1.f + expf(-x1));
        u[(base + r) * DFF + c0] = s0 * a20[r];
        u[(base + r) * DFF + c1] = s1 * a21[r];
    }
}

// -------- FFN part 2: q2 = qbuf + u @ w3, (4096x512)@(512x128) ---------------
__global__ __launch_bounds__(128) void ffn2_kernel(const float* __restrict__ u,
                                                   const float* __restrict__ w3,
                                                   const float* __restrict__ qbuf,
                                                   float* __restrict__ q2) {
    __shared__ float us[8][DFF];   // 16 KB
    int base = blockIdx.x * 8;
    int tid = threadIdx.x;
    for (int idx = tid; idx < 8 * DFF; idx += 128)
        us[idx >> 9][idx & 511] = u[base * DFF + idx];
    __syncthreads();
    float acc[8];
#pragma unroll
    for (int r = 0; r < 8; r++) acc[r] = 0.f;
    for (int k = 0; k < DFF; k += 4) {
        float w[4];
#pragma unroll
        for (int uu = 0; uu < 4; uu++) w[uu] = w3[(k + uu) * DA + tid];
#pragma unroll
        for (int r = 0; r < 8; r++) {
            float4 a = *(const float4*)&us[r][k];
            acc[r] += a.x * w[0] + a.y * w[1] + a.z * w[2] + a.w * w[3];
        }
    }
    for (int r = 0; r < 8; r++)
        q2[(base + r) * DA + tid] = qbuf[(base + r) * DA + tid] + acc[r];
}

// -------- token projection: af = q2 @ tok_w + tok_b, (4096x128)@(128x512) ----
__global__ __launch_bounds__(256) void tokproj_kernel(const float* __restrict__ q2,
                                                      const float* __restrict__ tw,
                                                      const float* __restrict__ tb,
                                                      float* __restrict__ af) {
    __shared__ float qs[16][DA];
    int base = blockIdx.x * 16;
    int tid = threadIdx.x;
    for (int idx = tid; idx < 16 * DA; idx += 256)
        qs[idx >> 7][idx & 127] = q2[base * DA + idx];
    __syncthreads();
    int c0 = tid, c1 = tid + 256;
    float acc0[16], acc1[16];
#pragma unroll
    for (int r = 0; r < 16; r++) { acc0[r] = 0.f; acc1[r] = 0.f; }
    for (int k = 0; k < DA; k += 4) {
        float w0[4], w1[4];
#pragma unroll
        for (int uu = 0; uu < 4; uu++) {
            w0[uu] = tw[(k + uu) * DM + c0];
            w1[uu] = tw[(k + uu) * DM + c1];
        }
#pragma unroll
        for (int r = 0; r < 16; r++) {
            float4 a = *(const float4*)&qs[r][k];
            acc0[r] += a.x * w0[0] + a.y * w0[1] + a.z * w0[2] + a.w * w0[3];
            acc1[r] += a.x * w1[0] + a.y * w1[1] + a.z * w1[2] + a.w * w1[3];
        }
    }
    float b0 = tb[c0], b1 = tb[c1];
    for (int r = 0; r < 16; r++) {
        af[(base + r) * DM + c0] = acc0[r] + b0;
        af[(base + r) * DM + c1] = acc1[r] + b1;
    }
}

// -------- segment mean over token groups -> out (B, NT, DM) ------------------
__global__ __launch_bounds__(128) void segmean_kernel(const float* __restrict__ af,
                                                      const int* __restrict__ tst,
                                                      const int* __restrict__ cnt,
                                                      float* __restrict__ out) {
    int blk = blockIdx.x;     // b*NT + t
    int b = blk >> 9;
    int tid = threadIdx.x;
    int start = tst[blk], n = cnt[blk];
    float acc[4] = {0.f, 0.f, 0.f, 0.f};
    for (int a = 0; a < n; a++) {
        const float* row = af + (b * N_ + start + a) * DM;
#pragma unroll
        for (int c = 0; c < 4; c++) acc[c] += row[tid + c * 128];
    }
    float inv = 1.f / fmaxf((float)n, 1.f);
#pragma unroll
    for (int c = 0; c < 4; c++) out[(size_t)blk * DM + tid + c * 128] = acc[c] * inv;
}

extern "C" void kernel_launch(void* const* d_in, const int* in_sizes, int n_in,
                              void* d_out, int out_size, void* d_ws, size_t ws_size,
                              hipStream_t stream) {
    const float* c_atom  = (const float*)d_in[0];
    const float* p_lm    = (const float*)d_in[1];
    const int*   p_idx   = (const int*)d_in[2];
    const int*   tok     = (const int*)d_in[3];
    // d_in[4] = n_tokens (512, hardcoded)
    const float* ln_a_g  = (const float*)d_in[5];
    const float* ln_a_b  = (const float*)d_in[6];
    const float* w_q     = (const float*)d_in[7];
    const float* w_k     = (const float*)d_in[8];
    const float* w_v     = (const float*)d_in[9];
    const float* w_g     = (const float*)d_in[10];
    const float* w_o     = (const float*)d_in[11];
    const float* pb_w    = (const float*)d_in[12];
    const float* pb_b    = (const float*)d_in[13];
    const float* ln_f_g  = (const float*)d_in[14];
    const float* ln_f_b  = (const float*)d_in[15];
    const float* sw_w1   = (const float*)d_in[16];
    const float* sw_w2   = (const float*)d_in[17];
    const float* sw_w3   = (const float*)d_in[18];
    const float* tok_w   = (const float*)d_in[19];
    const float* tok_b   = (const float*)d_in[20];
    float* out = (float*)d_out;

    // workspace layout (~28.3 MB)
    float* ws   = (float*)d_ws;
    float* qn   = ws;                           // 524288 f
    float* qkvg = qn + 524288;                  // 2097152 f
    int*   cnt  = (int*)(qkvg + 2097152);       // 1024 i
    int*   tst  = cnt + 1024;                   // 1024 i
    int*   win  = tst + 1024;                   // 262144 i
    float* bias = (float*)(win + 262144);       // 1048576 f
    float* att  = bias + 1048576;               // 524288 f
    float* qbuf = att + 524288;                 // 524288 f
    float* af   = qbuf + 524288;                // 2097152 f
    // aliases (lifetimes disjoint):
    float* hbuf = qn;     // after qkvg_kernel consumes qn
    float* ubuf = qkvg;   // after outproj consumes V,G
    float* q2   = att;    // after outproj consumes att

    hipMemsetAsync(cnt, 0, 1024 * sizeof(int), stream);
    hipMemsetAsync(win, 0xFF, 262144 * sizeof(int), stream);   // -1

    count_kernel<<<16, 256, 0, stream>>>(tok, cnt);
    scan_kernel<<<2, 64, 0, stream>>>(cnt, tst);

    ln_kernel<<<B_ * N_, 64, 0, stream>>>(c_atom, ln_a_g, ln_a_b, qn);
    qkvg_kernel<<<B_ * N_ / 16, 256, 0, stream>>>(qn, w_q, w_k, w_v, w_g, qkvg);

    pair_win_kernel<<<B_ * NP / 256, 256, 0, stream>>>(p_idx, tok, tst, win);
    pair_bias_kernel<<<B_ * NP / 256, 256, 0, stream>>>(p_idx, tok, tst, win,
                                                        p_lm, pb_w, pb_b, bias);

    attn_kernel<<<B_ * N_, 128, 0, stream>>>(qkvg, tok, tst, cnt, win, bias, att);
    outproj_kernel<<<B_ * N_ / 16, 128, 0, stream>>>(att, w_o, qkvg, c_atom, qbuf);

    ln_kernel<<<B_ * N_, 64, 0, stream>>>(qbuf, ln_f_g, ln_f_b, hbuf);
    ffn1_kernel<<<B_ * N_ / 16, 256, 0, stream>>>(hbuf, sw_w1, sw_w2, ubuf);
    ffn2_kernel<<<B_ * N_ / 8, 128, 0, stream>>>(ubuf, sw_w3, qbuf, q2);
    tokproj_kernel<<<B_ * N_ / 16, 256, 0, stream>>>(q2, tok_w, tok_b, af);

    segmean_kernel<<<B_ * NT, 128, 0, stream>>>(af, tst, cnt, out);
}

// Round 2
// 256.231 us; speedup vs baseline: 1.1042x; 1.1042x over previous
//
#include <hip/hip_runtime.h>
#include <hip/hip_bf16.h>
#include <math.h>

// Problem constants (fixed by setup_inputs)
#define B_     2
#define N_     2048
#define DA     128
#define H_     4
#define DH     32
#define DFF    512
#define DM     512
#define NT     512
#define NP     16384
#define MAXL   64          // max atoms per token group (Poisson(4): P(>64) ~ 0)

// ---------------- LayerNorm (one block = one row, 64 threads) ----------------
__global__ __launch_bounds__(64) void ln_kernel(const float* __restrict__ x,
                                                const float* __restrict__ g,
                                                const float* __restrict__ b,
                                                float* __restrict__ y) {
    int row = blockIdx.x;
    int t = threadIdx.x;
    const float* xr = x + row * DA;
    float a0 = xr[t], a1 = xr[t + 64];
    float s = a0 + a1, sq = a0 * a0 + a1 * a1;
#pragma unroll
    for (int m = 32; m; m >>= 1) {
        s += __shfl_xor(s, m);
        sq += __shfl_xor(sq, m);
    }
    float mean = s * (1.f / 128.f);
    float var = sq * (1.f / 128.f) - mean * mean;
    float inv = rsqrtf(var + 1e-5f);
    y[row * DA + t]      = (a0 - mean) * inv * g[t] + b[t];
    y[row * DA + t + 64] = (a1 - mean) * inv * g[t + 64] + b[t + 64];
}

// ---------------- fused histogram + exclusive scan (one block) ---------------
__global__ __launch_bounds__(1024) void hist_kernel(const int* __restrict__ tok,
                                                    int* __restrict__ cnt,
                                                    int* __restrict__ tst) {
    __shared__ int c[1024];
    __shared__ int s[1024];
    int tid = threadIdx.x;
    c[tid] = 0;
    __syncthreads();
#pragma unroll
    for (int i = 0; i < 4; i++) {
        int idx = tid + i * 1024;           // 0..4095
        int b = idx >> 11;
        atomicAdd(&c[b * NT + tok[idx]], 1);
    }
    __syncthreads();
    int t = tid & (NT - 1);
    int v = c[tid];
    // Hillis-Steele inclusive scan per 512-segment (ping-pong c <-> s)
    int* cur = c;
    int* alt = s;
    for (int d = 1; d < NT; d <<= 1) {
        int y = cur[tid];
        if (t >= d) y += cur[tid - d];
        alt[tid] = y;
        __syncthreads();
        int* tmp = cur; cur = alt; alt = tmp;
    }
    tst[tid] = cur[tid] - v;   // exclusive prefix
    cnt[tid] = v;
}

// ------------- QKVG projection: (4096x128) @ (128x512) -> qkvg ---------------
// out layout per row: [0:128)=Q, [128:256)=K, [256:384)=V, [384:512)=G
// Activations read via block-uniform addresses -> SMEM (s_load) path; no LDS.
__global__ __launch_bounds__(256) void qkvg_kernel(const float* __restrict__ qn,
                                                   const float* __restrict__ wq,
                                                   const float* __restrict__ wk,
                                                   const float* __restrict__ wv,
                                                   const float* __restrict__ wg,
                                                   float* __restrict__ out) {
    int base = blockIdx.x * 8;
    int tid = threadIdx.x;
    const float* wp0 = (tid < 128) ? (wq + tid) : (wk + tid - 128);
    const float* wp1 = (tid < 128) ? (wv + tid) : (wg + tid - 128);
    const float* ab = qn + base * DA;
    float acc0[8], acc1[8];
#pragma unroll
    for (int r = 0; r < 8; r++) { acc0[r] = 0.f; acc1[r] = 0.f; }
    for (int k = 0; k < DA; k += 4) {
        float w0[4], w1v[4];
#pragma unroll
        for (int u = 0; u < 4; u++) {
            w0[u]  = wp0[(k + u) * DA];
            w1v[u] = wp1[(k + u) * DA];
        }
#pragma unroll
        for (int r = 0; r < 8; r++) {
            float a0 = ab[r * DA + k], a1 = ab[r * DA + k + 1];
            float a2 = ab[r * DA + k + 2], a3 = ab[r * DA + k + 3];
            acc0[r] += a0 * w0[0] + a1 * w0[1] + a2 * w0[2] + a3 * w0[3];
            acc1[r] += a0 * w1v[0] + a1 * w1v[1] + a2 * w1v[2] + a3 * w1v[3];
        }
    }
    int c0 = tid, c1 = tid + 256;
    for (int r = 0; r < 8; r++) {
        out[(base + r) * 512 + c0] = acc0[r];
        out[(base + r) * 512 + c1] = acc1[r];
    }
}

// ---------------- pair bias: winner pass (last-write-wins = max pair idx) ----
__global__ void pair_win_kernel(const int* __restrict__ pidx,
                                const int* __restrict__ tok,
                                const int* __restrict__ tst,
                                int* __restrict__ winner) {
    int p = blockIdx.x * 256 + threadIdx.x;   // 0..32767
    if (p >= B_ * NP) return;
    int b = p >> 14, pp = p & (NP - 1);
    int src = pidx[p * 2], dst = pidx[p * 2 + 1];
    int ts = tok[b * N_ + src], td = tok[b * N_ + dst];
    if (ts == td) {
        int jj = dst - tst[b * NT + td];
        if (jj < MAXL) atomicMax(&winner[(b * N_ + src) * MAXL + jj], pp);
    }
}

__global__ void pair_bias_kernel(const int* __restrict__ pidx,
                                 const int* __restrict__ tok,
                                 const int* __restrict__ tst,
                                 const int* __restrict__ winner,
                                 const float* __restrict__ plm,
                                 const float* __restrict__ pbw,
                                 const float* __restrict__ pbb,
                                 float* __restrict__ biasc) {
    int p = blockIdx.x * 256 + threadIdx.x;
    if (p >= B_ * NP) return;
    int b = p >> 14, pp = p & (NP - 1);
    int src = pidx[p * 2], dst = pidx[p * 2 + 1];
    int ts = tok[b * N_ + src], td = tok[b * N_ + dst];
    if (ts == td) {
        int jj = dst - tst[b * NT + td];
        if (jj < MAXL && winner[(b * N_ + src) * MAXL + jj] == pp) {
            const float* pl = plm + p * 16;
#pragma unroll
            for (int h = 0; h < H_; h++) {
                float s = pbb[h];
#pragma unroll
                for (int f = 0; f < 16; f++) s += pl[f] * pbw[f * H_ + h];
                biasc[((b * N_ + src) * MAXL + jj) * H_ + h] = s;
            }
        }
    }
}

// ---------------- grouped attention (one block per atom, 128 thr = 4h x 32d) -
__global__ __launch_bounds__(128) void attn_kernel(const float* __restrict__ qkvg,
                                                   const int* __restrict__ tok,
                                                   const int* __restrict__ tst,
                                                   const int* __restrict__ cnt,
                                                   const int* __restrict__ winner,
                                                   const float* __restrict__ biasc,
                                                   float* __restrict__ att) {
    __shared__ float sc[H_][MAXL];
    int blk = blockIdx.x;                 // b*2048 + i
    int b = blk >> 11;
    int h = threadIdx.x >> 5, d = threadIdx.x & 31;
    int t = tok[blk];
    int start = tst[b * NT + t];
    int L = cnt[b * NT + t];
    if (L > MAXL) L = MAXL;
    float qv = qkvg[blk * 512 + h * DH + d];
    const float scale = 0.17677669529663687f;   // 1/sqrt(32)
    for (int jj = 0; jj < L; jj++) {
        int j = b * N_ + start + jj;
        float kv = qkvg[j * 512 + 128 + h * DH + d];
        float s = qv * kv;
#pragma unroll
        for (int m = 16; m; m >>= 1) s += __shfl_xor(s, m, 32);
        s *= scale;
        if (winner[blk * MAXL + jj] >= 0) s += biasc[(blk * MAXL + jj) * H_ + h];
        if (d == 0) sc[h][jj] = s;
    }
    __syncthreads();
    float mx = -1e30f;
    for (int jj = 0; jj < L; jj++) mx = fmaxf(mx, sc[h][jj]);
    float denom = 0.f, acc = 0.f;
    for (int jj = 0; jj < L; jj++) {
        float pj = expf(sc[h][jj] - mx);
        denom += pj;
        acc += pj * qkvg[(b * N_ + start + jj) * 512 + 256 + h * DH + d];
    }
    att[blk * DA + h * DH + d] = acc / denom;
}

// -------- out-proj + gate: qbuf = c_atom + sigmoid(G) * (att @ w_o) ----------
__global__ __launch_bounds__(128) void outproj_kernel(const float* __restrict__ att,
                                                      const float* __restrict__ wo,
                                                      const float* __restrict__ qkvg,
                                                      const float* __restrict__ c_atom,
                                                      float* __restrict__ qbuf) {
    int base = blockIdx.x * 8;
    int tid = threadIdx.x;     // column 0..127
    const float* ab = att + base * DA;
    float acc[8];
#pragma unroll
    for (int r = 0; r < 8; r++) acc[r] = 0.f;
    for (int k = 0; k < DA; k += 4) {
        float w[4];
#pragma unroll
        for (int u = 0; u < 4; u++) w[u] = wo[(k + u) * DA + tid];
#pragma unroll
        for (int r = 0; r < 8; r++) {
            float a0 = ab[r * DA + k], a1 = ab[r * DA + k + 1];
            float a2 = ab[r * DA + k + 2], a3 = ab[r * DA + k + 3];
            acc[r] += a0 * w[0] + a1 * w[1] + a2 * w[2] + a3 * w[3];
        }
    }
    for (int r = 0; r < 8; r++) {
        int row = base + r;
        float g = qkvg[row * 512 + 384 + tid];
        float sg = 1.f / (1.f + expf(-g));
        qbuf[row * DA + tid] = c_atom[row * DA + tid] + sg * acc[r];
    }
}

// -------- FFN part 1: u = silu(h@w1) * (h@w2), (4096x128)@(128x512) ----------
__global__ __launch_bounds__(256) void ffn1_kernel(const float* __restrict__ h,
                                                   const float* __restrict__ w1,
                                                   const float* __restrict__ w2,
                                                   float* __restrict__ u) {
    int base = blockIdx.x * 8;
    int tid = threadIdx.x;
    int c0 = tid, c1 = tid + 256;
    const float* hb = h + base * DA;
    float a10[8], a11[8], a20[8], a21[8];
#pragma unroll
    for (int r = 0; r < 8; r++) { a10[r] = 0.f; a11[r] = 0.f; a20[r] = 0.f; a21[r] = 0.f; }
    for (int k = 0; k < DA; k += 4) {
        float w10[4], w11[4], w20[4], w21[4];
#pragma unroll
        for (int uu = 0; uu < 4; uu++) {
            w10[uu] = w1[(k + uu) * DFF + c0];
            w11[uu] = w1[(k + uu) * DFF + c1];
            w20[uu] = w2[(k + uu) * DFF + c0];
            w21[uu] = w2[(k + uu) * DFF + c1];
        }
#pragma unroll
        for (int r = 0; r < 8; r++) {
            float a0 = hb[r * DA + k], a1 = hb[r * DA + k + 1];
            float a2 = hb[r * DA + k + 2], a3 = hb[r * DA + k + 3];
            a10[r] += a0 * w10[0] + a1 * w10[1] + a2 * w10[2] + a3 * w10[3];
            a11[r] += a0 * w11[0] + a1 * w11[1] + a2 * w11[2] + a3 * w11[3];
            a20[r] += a0 * w20[0] + a1 * w20[1] + a2 * w20[2] + a3 * w20[3];
            a21[r] += a0 * w21[0] + a1 * w21[1] + a2 * w21[2] + a3 * w21[3];
        }
    }
    for (int r = 0; r < 8; r++) {
        float x0 = a10[r], x1 = a11[r];
        float s0 = x0 / (1.f + expf(-x0));
        float s1 = x1 / (1.f + expf(-x1));
        u[(base + r) * DFF + c0] = s0 * a20[r];
        u[(base + r) * DFF + c1] = s1 * a21[r];
    }
}

// -------- FFN part 2: q2 = qbuf + u @ w3, (4096x512)@(512x128) ---------------
__global__ __launch_bounds__(128) void ffn2_kernel(const float* __restrict__ u,
                                                   const float* __restrict__ w3,
                                                   const float* __restrict__ qbuf,
                                                   float* __restrict__ q2) {
    int base = blockIdx.x * 8;
    int tid = threadIdx.x;
    const float* ub = u + base * DFF;
    float acc[8];
#pragma unroll
    for (int r = 0; r < 8; r++) acc[r] = 0.f;
    for (int k = 0; k < DFF; k += 4) {
        float w[4];
#pragma unroll
        for (int uu = 0; uu < 4; uu++) w[uu] = w3[(k + uu) * DA + tid];
#pragma unroll
        for (int r = 0; r < 8; r++) {
            float a0 = ub[r * DFF + k], a1 = ub[r * DFF + k + 1];
            float a2 = ub[r * DFF + k + 2], a3 = ub[r * DFF + k + 3];
            acc[r] += a0 * w[0] + a1 * w[1] + a2 * w[2] + a3 * w[3];
        }
    }
    for (int r = 0; r < 8; r++)
        q2[(base + r) * DA + tid] = qbuf[(base + r) * DA + tid] + acc[r];
}

// -------- token projection: af = q2 @ tok_w + tok_b, (4096x128)@(128x512) ----
__global__ __launch_bounds__(256) void tokproj_kernel(const float* __restrict__ q2,
                                                      const float* __restrict__ tw,
                                                      const float* __restrict__ tb,
                                                      float* __restrict__ af) {
    int base = blockIdx.x * 8;
    int tid = threadIdx.x;
    int c0 = tid, c1 = tid + 256;
    const float* qb = q2 + base * DA;
    float acc0[8], acc1[8];
#pragma unroll
    for (int r = 0; r < 8; r++) { acc0[r] = 0.f; acc1[r] = 0.f; }
    for (int k = 0; k < DA; k += 4) {
        float w0[4], w1v[4];
#pragma unroll
        for (int uu = 0; uu < 4; uu++) {
            w0[uu]  = tw[(k + uu) * DM + c0];
            w1v[uu] = tw[(k + uu) * DM + c1];
        }
#pragma unroll
        for (int r = 0; r < 8; r++) {
            float a0 = qb[r * DA + k], a1 = qb[r * DA + k + 1];
            float a2 = qb[r * DA + k + 2], a3 = qb[r * DA + k + 3];
            acc0[r] += a0 * w0[0] + a1 * w0[1] + a2 * w0[2] + a3 * w0[3];
            acc1[r] += a0 * w1v[0] + a1 * w1v[1] + a2 * w1v[2] + a3 * w1v[3];
        }
    }
    float b0 = tb[c0], b1 = tb[c1];
    for (int r = 0; r < 8; r++) {
        af[(base + r) * DM + c0] = acc0[r] + b0;
        af[(base + r) * DM + c1] = acc1[r] + b1;
    }
}

// -------- segment mean over token groups -> out (B, NT, DM) ------------------
__global__ __launch_bounds__(128) void segmean_kernel(const float* __restrict__ af,
                                                      const int* __restrict__ tst,
                                                      const int* __restrict__ cnt,
                                                      float* __restrict__ out) {
    int blk = blockIdx.x;     // b*NT + t
    int b = blk >> 9;
    int tid = threadIdx.x;
    int start = tst[blk], n = cnt[blk];
    float acc[4] = {0.f, 0.f, 0.f, 0.f};
    for (int a = 0; a < n; a++) {
        const float* row = af + (b * N_ + start + a) * DM;
#pragma unroll
        for (int c = 0; c < 4; c++) acc[c] += row[tid + c * 128];
    }
    float inv = 1.f / fmaxf((float)n, 1.f);
#pragma unroll
    for (int c = 0; c < 4; c++) out[(size_t)blk * DM + tid + c * 128] = acc[c] * inv;
}

extern "C" void kernel_launch(void* const* d_in, const int* in_sizes, int n_in,
                              void* d_out, int out_size, void* d_ws, size_t ws_size,
                              hipStream_t stream) {
    const float* c_atom  = (const float*)d_in[0];
    const float* p_lm    = (const float*)d_in[1];
    const int*   p_idx   = (const int*)d_in[2];
    const int*   tok     = (const int*)d_in[3];
    // d_in[4] = n_tokens (512, hardcoded)
    const float* ln_a_g  = (const float*)d_in[5];
    const float* ln_a_b  = (const float*)d_in[6];
    const float* w_q     = (const float*)d_in[7];
    const float* w_k     = (const float*)d_in[8];
    const float* w_v     = (const float*)d_in[9];
    const float* w_g     = (const float*)d_in[10];
    const float* w_o     = (const float*)d_in[11];
    const float* pb_w    = (const float*)d_in[12];
    const float* pb_b    = (const float*)d_in[13];
    const float* ln_f_g  = (const float*)d_in[14];
    const float* ln_f_b  = (const float*)d_in[15];
    const float* sw_w1   = (const float*)d_in[16];
    const float* sw_w2   = (const float*)d_in[17];
    const float* sw_w3   = (const float*)d_in[18];
    const float* tok_w   = (const float*)d_in[19];
    const float* tok_b   = (const float*)d_in[20];
    float* out = (float*)d_out;

    // workspace layout (~28.3 MB)
    float* ws   = (float*)d_ws;
    float* qn   = ws;                           // 524288 f
    float* qkvg = qn + 524288;                  // 2097152 f
    int*   cnt  = (int*)(qkvg + 2097152);       // 1024 i
    int*   tst  = cnt + 1024;                   // 1024 i
    int*   win  = tst + 1024;                   // 262144 i
    float* bias = (float*)(win + 262144);       // 1048576 f
    float* att  = bias + 1048576;               // 524288 f
    float* qbuf = att + 524288;                 // 524288 f
    float* af   = qbuf + 524288;                // 2097152 f
    // aliases (lifetimes disjoint):
    float* hbuf = qn;     // after qkvg_kernel consumes qn
    float* ubuf = qkvg;   // after outproj consumes V,G
    float* q2   = att;    // after outproj consumes att

    hipMemsetAsync(win, 0xFF, 262144 * sizeof(int), stream);   // -1

    hist_kernel<<<1, 1024, 0, stream>>>(tok, cnt, tst);

    ln_kernel<<<B_ * N_, 64, 0, stream>>>(c_atom, ln_a_g, ln_a_b, qn);
    qkvg_kernel<<<B_ * N_ / 8, 256, 0, stream>>>(qn, w_q, w_k, w_v, w_g, qkvg);

    pair_win_kernel<<<B_ * NP / 256, 256, 0, stream>>>(p_idx, tok, tst, win);
    pair_bias_kernel<<<B_ * NP / 256, 256, 0, stream>>>(p_idx, tok, tst, win,
                                                        p_lm, pb_w, pb_b, bias);

    attn_kernel<<<B_ * N_, 128, 0, stream>>>(qkvg, tok, tst, cnt, win, bias, att);
    outproj_kernel<<<B_ * N_ / 8, 128, 0, stream>>>(att, w_o, qkvg, c_atom, qbuf);

    ln_kernel<<<B_ * N_, 64, 0, stream>>>(qbuf, ln_f_g, ln_f_b, hbuf);
    ffn1_kernel<<<B_ * N_ / 8, 256, 0, stream>>>(hbuf, sw_w1, sw_w2, ubuf);
    ffn2_kernel<<<B_ * N_ / 8, 128, 0, stream>>>(ubuf, sw_w3, qbuf, q2);
    tokproj_kernel<<<B_ * N_ / 8, 256, 0, stream>>>(q2, tok_w, tok_b, af);

    segmean_kernel<<<B_ * NT, 128, 0, stream>>>(af, tst, cnt, out);
}

// Round 3
// 223.348 us; speedup vs baseline: 1.2668x; 1.1472x over previous
//
#include <hip/hip_runtime.h>
#include <hip/hip_bf16.h>
#include <math.h>

// Problem constants (fixed by setup_inputs)
#define B_     2
#define N_     2048
#define DA     128
#define H_     4
#define DH     32
#define DFF    512
#define DM     512
#define NT     512
#define NP     16384
#define MAXL   64          // max atoms per token group (Poisson(4): P(>64) ~ 0)

// ---------------- LayerNorm (one block = one row, 64 threads) ----------------
__global__ __launch_bounds__(64) void ln_kernel(const float* __restrict__ x,
                                                const float* __restrict__ g,
                                                const float* __restrict__ b,
                                                float* __restrict__ y) {
    int row = blockIdx.x;
    int t = threadIdx.x;
    const float* xr = x + row * DA;
    float a0 = xr[t], a1 = xr[t + 64];
    float s = a0 + a1, sq = a0 * a0 + a1 * a1;
#pragma unroll
    for (int m = 32; m; m >>= 1) {
        s += __shfl_xor(s, m);
        sq += __shfl_xor(sq, m);
    }
    float mean = s * (1.f / 128.f);
    float var = sq * (1.f / 128.f) - mean * mean;
    float inv = rsqrtf(var + 1e-5f);
    y[row * DA + t]      = (a0 - mean) * inv * g[t] + b[t];
    y[row * DA + t + 64] = (a1 - mean) * inv * g[t + 64] + b[t + 64];
}

// ---------------- fused histogram + exclusive scan (one block) ---------------
__global__ __launch_bounds__(1024) void hist_kernel(const int* __restrict__ tok,
                                                    int* __restrict__ cnt,
                                                    int* __restrict__ tst) {
    __shared__ int c[1024];
    __shared__ int s[1024];
    int tid = threadIdx.x;
    c[tid] = 0;
    __syncthreads();
#pragma unroll
    for (int i = 0; i < 4; i++) {
        int idx = tid + i * 1024;           // 0..4095
        int b = idx >> 11;
        atomicAdd(&c[b * NT + tok[idx]], 1);
    }
    __syncthreads();
    int t = tid & (NT - 1);
    int v = c[tid];
    int* cur = c;
    int* alt = s;
    for (int d = 1; d < NT; d <<= 1) {
        int y = cur[tid];
        if (t >= d) y += cur[tid - d];
        alt[tid] = y;
        __syncthreads();
        int* tmp = cur; cur = alt; alt = tmp;
    }
    tst[tid] = cur[tid] - v;   // exclusive prefix
    cnt[tid] = v;
}

// ------------- QKVG projection: (4096x128) @ (128x512) -> qkvg ---------------
// grid (512, 2), 256 thr; 8 rows/block, 1 col/thread. Activations via SMEM.
__global__ __launch_bounds__(256) void qkvg_kernel(const float* __restrict__ qn,
                                                   const float* __restrict__ wq,
                                                   const float* __restrict__ wk,
                                                   const float* __restrict__ wv,
                                                   const float* __restrict__ wg,
                                                   float* __restrict__ out) {
    int base = blockIdx.x * 8;
    int col = blockIdx.y * 256 + threadIdx.x;     // 0..511
    const float* wsel = (col < 128) ? wq : (col < 256) ? wk : (col < 384) ? wv : wg;
    const float* wp = wsel + (col & 127);
    const float* ab = qn + base * DA;
    float acc[8];
#pragma unroll
    for (int r = 0; r < 8; r++) acc[r] = 0.f;
#pragma unroll
    for (int k = 0; k < DA; k += 4) {
        float w[4];
#pragma unroll
        for (int u = 0; u < 4; u++) w[u] = wp[(k + u) * DA];
#pragma unroll
        for (int r = 0; r < 8; r++) {
#pragma unroll
            for (int u = 0; u < 4; u++) acc[r] += ab[r * DA + k + u] * w[u];
        }
    }
    for (int r = 0; r < 8; r++) out[(base + r) * 512 + col] = acc[r];
}

// ---------------- pair bias: winner pass (last-write-wins = max pair idx) ----
__global__ void pair_win_kernel(const int* __restrict__ pidx,
                                const int* __restrict__ tok,
                                const int* __restrict__ tst,
                                int* __restrict__ winner) {
    int p = blockIdx.x * 256 + threadIdx.x;   // 0..32767
    if (p >= B_ * NP) return;
    int b = p >> 14, pp = p & (NP - 1);
    int src = pidx[p * 2], dst = pidx[p * 2 + 1];
    int ts = tok[b * N_ + src], td = tok[b * N_ + dst];
    if (ts == td) {
        int jj = dst - tst[b * NT + td];
        if (jj < MAXL) atomicMax(&winner[(b * N_ + src) * MAXL + jj], pp);
    }
}

__global__ void pair_bias_kernel(const int* __restrict__ pidx,
                                 const int* __restrict__ tok,
                                 const int* __restrict__ tst,
                                 const int* __restrict__ winner,
                                 const float* __restrict__ plm,
                                 const float* __restrict__ pbw,
                                 const float* __restrict__ pbb,
                                 float* __restrict__ biasc) {
    int p = blockIdx.x * 256 + threadIdx.x;
    if (p >= B_ * NP) return;
    int b = p >> 14, pp = p & (NP - 1);
    int src = pidx[p * 2], dst = pidx[p * 2 + 1];
    int ts = tok[b * N_ + src], td = tok[b * N_ + dst];
    if (ts == td) {
        int jj = dst - tst[b * NT + td];
        if (jj < MAXL && winner[(b * N_ + src) * MAXL + jj] == pp) {
            const float* pl = plm + p * 16;
#pragma unroll
            for (int h = 0; h < H_; h++) {
                float s = pbb[h];
#pragma unroll
                for (int f = 0; f < 16; f++) s += pl[f] * pbw[f * H_ + h];
                biasc[((b * N_ + src) * MAXL + jj) * H_ + h] = s;
            }
        }
    }
}

// ---------------- grouped attention (one block per atom, 128 thr = 4h x 32d) -
__global__ __launch_bounds__(128) void attn_kernel(const float* __restrict__ qkvg,
                                                   const int* __restrict__ tok,
                                                   const int* __restrict__ tst,
                                                   const int* __restrict__ cnt,
                                                   const int* __restrict__ winner,
                                                   const float* __restrict__ biasc,
                                                   float* __restrict__ att) {
    __shared__ float sc[H_][MAXL];
    int blk = blockIdx.x;                 // b*2048 + i
    int b = blk >> 11;
    int h = threadIdx.x >> 5, d = threadIdx.x & 31;
    int t = tok[blk];
    int start = tst[b * NT + t];
    int L = cnt[b * NT + t];
    if (L > MAXL) L = MAXL;
    float qv = qkvg[blk * 512 + h * DH + d];
    const float scale = 0.17677669529663687f;   // 1/sqrt(32)
    for (int jj = 0; jj < L; jj++) {
        int j = b * N_ + start + jj;
        float kv = qkvg[j * 512 + 128 + h * DH + d];
        float s = qv * kv;
#pragma unroll
        for (int m = 16; m; m >>= 1) s += __shfl_xor(s, m, 32);
        s *= scale;
        if (winner[blk * MAXL + jj] >= 0) s += biasc[(blk * MAXL + jj) * H_ + h];
        if (d == 0) sc[h][jj] = s;
    }
    __syncthreads();
    float mx = -1e30f;
    for (int jj = 0; jj < L; jj++) mx = fmaxf(mx, sc[h][jj]);
    float denom = 0.f, acc = 0.f;
    for (int jj = 0; jj < L; jj++) {
        float pj = expf(sc[h][jj] - mx);
        denom += pj;
        acc += pj * qkvg[(b * N_ + start + jj) * 512 + 256 + h * DH + d];
    }
    att[blk * DA + h * DH + d] = acc / denom;
}

// -------- out-proj + gate: qbuf = c_atom + sigmoid(G) * (att @ w_o) ----------
// 256 thr = wave-pair row split: half 0 -> rows 0-3, half 1 -> rows 4-7.
__global__ __launch_bounds__(256) void outproj_kernel(const float* __restrict__ att,
                                                      const float* __restrict__ wo,
                                                      const float* __restrict__ qkvg,
                                                      const float* __restrict__ c_atom,
                                                      float* __restrict__ qbuf) {
    int half = threadIdx.x >> 7;
    int col = threadIdx.x & 127;
    int base = blockIdx.x * 8 + half * 4;
    const float* ab = att + base * DA;
    float acc[4];
#pragma unroll
    for (int r = 0; r < 4; r++) acc[r] = 0.f;
#pragma unroll
    for (int k = 0; k < DA; k += 4) {
        float w[4];
#pragma unroll
        for (int u = 0; u < 4; u++) w[u] = wo[(k + u) * DA + col];
#pragma unroll
        for (int r = 0; r < 4; r++) {
#pragma unroll
            for (int u = 0; u < 4; u++) acc[r] += ab[r * DA + k + u] * w[u];
        }
    }
    for (int r = 0; r < 4; r++) {
        int row = base + r;
        float g = qkvg[row * 512 + 384 + col];
        float sg = 1.f / (1.f + expf(-g));
        qbuf[row * DA + col] = c_atom[row * DA + col] + sg * acc[r];
    }
}

// -------- FFN part 1: u = silu(h@w1) * (h@w2), grid (512,2), 1 col/thread ----
__global__ __launch_bounds__(256) void ffn1_kernel(const float* __restrict__ h,
                                                   const float* __restrict__ w1,
                                                   const float* __restrict__ w2,
                                                   float* __restrict__ u) {
    int base = blockIdx.x * 8;
    int col = blockIdx.y * 256 + threadIdx.x;   // 0..511
    const float* hb = h + base * DA;
    float a1[8], a2[8];
#pragma unroll
    for (int r = 0; r < 8; r++) { a1[r] = 0.f; a2[r] = 0.f; }
#pragma unroll 8
    for (int k = 0; k < DA; k += 4) {
        float w1v[4], w2v[4];
#pragma unroll
        for (int uu = 0; uu < 4; uu++) {
            w1v[uu] = w1[(k + uu) * DFF + col];
            w2v[uu] = w2[(k + uu) * DFF + col];
        }
#pragma unroll
        for (int r = 0; r < 8; r++) {
#pragma unroll
            for (int uu = 0; uu < 4; uu++) {
                a1[r] += hb[r * DA + k + uu] * w1v[uu];
                a2[r] += hb[r * DA + k + uu] * w2v[uu];
            }
        }
    }
    for (int r = 0; r < 8; r++) {
        float x = a1[r];
        float s = x / (1.f + expf(-x));
        u[(base + r) * DFF + col] = s * a2[r];
    }
}

// -------- FFN part 2 (split-K): q2 += u @ w3 partial over K-slice of 128 -----
// grid (512, 4), 128 thr. q2 pre-initialized to qbuf (residual).
__global__ __launch_bounds__(128) void ffn2_kernel(const float* __restrict__ u,
                                                   const float* __restrict__ w3,
                                                   float* __restrict__ q2) {
    int base = blockIdx.x * 8;
    int ks = blockIdx.y * 128;
    int tid = threadIdx.x;
    const float* ub = u + base * DFF + ks;
    const float* wp = w3 + ks * DA + tid;
    float acc[8];
#pragma unroll
    for (int r = 0; r < 8; r++) acc[r] = 0.f;
#pragma unroll
    for (int k = 0; k < 128; k += 4) {
        float w[4];
#pragma unroll
        for (int uu = 0; uu < 4; uu++) w[uu] = wp[(k + uu) * DA];
#pragma unroll
        for (int r = 0; r < 8; r++) {
#pragma unroll
            for (int uu = 0; uu < 4; uu++) acc[r] += ub[r * DFF + k + uu] * w[uu];
        }
    }
    for (int r = 0; r < 8; r++)
        atomicAdd(&q2[(base + r) * DA + tid], acc[r]);
}

// -------- token projection: af = q2 @ tok_w + tok_b, grid (512,2) ------------
__global__ __launch_bounds__(256) void tokproj_kernel(const float* __restrict__ q2,
                                                      const float* __restrict__ tw,
                                                      const float* __restrict__ tb,
                                                      float* __restrict__ af) {
    int base = blockIdx.x * 8;
    int col = blockIdx.y * 256 + threadIdx.x;
    const float* qb = q2 + base * DA;
    float acc[8];
#pragma unroll
    for (int r = 0; r < 8; r++) acc[r] = 0.f;
#pragma unroll
    for (int k = 0; k < DA; k += 4) {
        float w[4];
#pragma unroll
        for (int uu = 0; uu < 4; uu++) w[uu] = tw[(k + uu) * DM + col];
#pragma unroll
        for (int r = 0; r < 8; r++) {
#pragma unroll
            for (int uu = 0; uu < 4; uu++) acc[r] += qb[r * DA + k + uu] * w[uu];
        }
    }
    float bv = tb[col];
    for (int r = 0; r < 8; r++) af[(base + r) * DM + col] = acc[r] + bv;
}

// -------- segment mean over token groups -> out (B, NT, DM) ------------------
__global__ __launch_bounds__(128) void segmean_kernel(const float* __restrict__ af,
                                                      const int* __restrict__ tst,
                                                      const int* __restrict__ cnt,
                                                      float* __restrict__ out) {
    int blk = blockIdx.x;     // b*NT + t
    int b = blk >> 9;
    int tid = threadIdx.x;
    int start = tst[blk], n = cnt[blk];
    float acc[4] = {0.f, 0.f, 0.f, 0.f};
    for (int a = 0; a < n; a++) {
        const float* row = af + (b * N_ + start + a) * DM;
#pragma unroll
        for (int c = 0; c < 4; c++) acc[c] += row[tid + c * 128];
    }
    float inv = 1.f / fmaxf((float)n, 1.f);
#pragma unroll
    for (int c = 0; c < 4; c++) out[(size_t)blk * DM + tid + c * 128] = acc[c] * inv;
}

extern "C" void kernel_launch(void* const* d_in, const int* in_sizes, int n_in,
                              void* d_out, int out_size, void* d_ws, size_t ws_size,
                              hipStream_t stream) {
    const float* c_atom  = (const float*)d_in[0];
    const float* p_lm    = (const float*)d_in[1];
    const int*   p_idx   = (const int*)d_in[2];
    const int*   tok     = (const int*)d_in[3];
    // d_in[4] = n_tokens (512, hardcoded)
    const float* ln_a_g  = (const float*)d_in[5];
    const float* ln_a_b  = (const float*)d_in[6];
    const float* w_q     = (const float*)d_in[7];
    const float* w_k     = (const float*)d_in[8];
    const float* w_v     = (const float*)d_in[9];
    const float* w_g     = (const float*)d_in[10];
    const float* w_o     = (const float*)d_in[11];
    const float* pb_w    = (const float*)d_in[12];
    const float* pb_b    = (const float*)d_in[13];
    const float* ln_f_g  = (const float*)d_in[14];
    const float* ln_f_b  = (const float*)d_in[15];
    const float* sw_w1   = (const float*)d_in[16];
    const float* sw_w2   = (const float*)d_in[17];
    const float* sw_w3   = (const float*)d_in[18];
    const float* tok_w   = (const float*)d_in[19];
    const float* tok_b   = (const float*)d_in[20];
    float* out = (float*)d_out;

    // workspace layout (~28.3 MB)
    float* ws   = (float*)d_ws;
    float* qn   = ws;                           // 524288 f
    float* qkvg = qn + 524288;                  // 2097152 f
    int*   cnt  = (int*)(qkvg + 2097152);       // 1024 i
    int*   tst  = cnt + 1024;                   // 1024 i
    int*   win  = tst + 1024;                   // 262144 i
    float* bias = (float*)(win + 262144);       // 1048576 f
    float* att  = bias + 1048576;               // 524288 f
    float* qbuf = att + 524288;                 // 524288 f
    float* af   = qbuf + 524288;                // 2097152 f
    // aliases (lifetimes disjoint):
    float* hbuf = qn;     // after qkvg_kernel consumes qn
    float* ubuf = qkvg;   // after outproj consumes V,G
    float* q2   = att;    // after outproj consumes att

    hipMemsetAsync(win, 0xFF, 262144 * sizeof(int), stream);   // -1

    hist_kernel<<<1, 1024, 0, stream>>>(tok, cnt, tst);

    ln_kernel<<<B_ * N_, 64, 0, stream>>>(c_atom, ln_a_g, ln_a_b, qn);
    qkvg_kernel<<<dim3(B_ * N_ / 8, 2), 256, 0, stream>>>(qn, w_q, w_k, w_v, w_g, qkvg);

    pair_win_kernel<<<B_ * NP / 256, 256, 0, stream>>>(p_idx, tok, tst, win);
    pair_bias_kernel<<<B_ * NP / 256, 256, 0, stream>>>(p_idx, tok, tst, win,
                                                        p_lm, pb_w, pb_b, bias);

    attn_kernel<<<B_ * N_, 128, 0, stream>>>(qkvg, tok, tst, cnt, win, bias, att);
    outproj_kernel<<<B_ * N_ / 8, 256, 0, stream>>>(att, w_o, qkvg, c_atom, qbuf);

    ln_kernel<<<B_ * N_, 64, 0, stream>>>(qbuf, ln_f_g, ln_f_b, hbuf);
    ffn1_kernel<<<dim3(B_ * N_ / 8, 2), 256, 0, stream>>>(hbuf, sw_w1, sw_w2, ubuf);

    // q2 = qbuf (residual init), then split-K ffn2 atomically accumulates
    hipMemcpyAsync(q2, qbuf, 524288 * sizeof(float), hipMemcpyDeviceToDevice, stream);
    ffn2_kernel<<<dim3(B_ * N_ / 8, 4), 128, 0, stream>>>(ubuf, sw_w3, q2);

    tokproj_kernel<<<dim3(B_ * N_ / 8, 2), 256, 0, stream>>>(q2, tok_w, tok_b, af);

    segmean_kernel<<<B_ * NT, 128, 0, stream>>>(af, tst, cnt, out);
}